// Round 9
// baseline (631.706 us; speedup 1.0000x reference)
//
#include <hip/hip_runtime.h>
#include <hip/hip_bf16.h>

// Problem constants (match reference)
constexpr int BB = 16384;   // batch
constexpr int CC = 2048;    // classes
constexpr int DD = 256;     // dim
constexpr float THR   = 0.8f;
constexpr float EPSN  = 1e-8f;

typedef __bf16 bf16x8 __attribute__((ext_vector_type(8)));
typedef float  f32x4  __attribute__((ext_vector_type(4)));

// ROUND-9 MEASUREMENT ROUND: every kernel amplified past the 75us poison-fill
// floor so all three surface in rocprof top-5 with their true counters.
// REP_SCAN=4, REP_CN=32, REP_LOSS=8 (scale 1/8). All reps idempotent in
// effect; per-kernel true duration = measured / REP.
constexpr int REP_SCAN = 4;
constexpr int REP_CN   = 32;
constexpr int REP_LOSS = 8;   // 32 linearized K-steps below

// ---------------- workspace layout (bytes) ----------------
// [0)         cls    : B*4   = 65,536    (fully rewritten every call)
// [65,536)    exists : C*4   = 8,192     (fully rewritten every call)
// [73,728)    Ecnt   : 4 (pad to 73,792) (zeroed by k_scan_pn)
// [73,792)    pn     : B*D*2 = 8,388,608 (bf16, fully rewritten)
// [8,462,400) cn     : C*D*2 = 1,048,576 (bf16, fully rewritten)
constexpr int SLOTS = 48;   // max rows/class; P(Binom(16384,1/2048) > 48) ~ 1e-30

// K1: blocks [0,2048) stream labels -> cls[row] (one-hot: one writer/row, no
// atomics) + zero out/Ecnt; blocks [2048,6144) normalize preds -> pn bf16.
__global__ __launch_bounds__(256) void k_scan_pn(const float* __restrict__ labels,
                                                 const float* __restrict__ preds,
                                                 int* __restrict__ cls,
                                                 unsigned short* __restrict__ pn,
                                                 int* __restrict__ Ecnt,
                                                 float* __restrict__ out) {
  for (int rep = 0; rep < REP_SCAN; ++rep) {
    if (blockIdx.x < 2048) {
      if (blockIdx.x == 0 && threadIdx.x == 0) { *out = 0.f; *Ecnt = 0; }
      constexpr size_t total = (size_t)BB * CC / 4;
      size_t q = (size_t)blockIdx.x * 256 + threadIdx.x;
      const float4* l4 = reinterpret_cast<const float4*>(labels);
      for (; q < total; q += 2048 * 256) {
        float4 v = l4[q];
        if (v.x >= THR || v.y >= THR || v.z >= THR || v.w >= THR) {
          int f = (int)(q * 4);
          int row = f >> 11;      // / CC
          int col = f & (CC - 1);
          cls[row] = col + (v.x >= THR ? 0 : v.y >= THR ? 1 : v.z >= THR ? 2 : 3);
        }
      }
    } else {
      int b = (blockIdx.x - 2048) * 4 + (threadIdx.x >> 6);
      int lane = threadIdx.x & 63;
      float4 v = reinterpret_cast<const float4*>(preds + (size_t)b * DD)[lane];
      float s = v.x * v.x + v.y * v.y + v.z * v.z + v.w * v.w;
#pragma unroll
      for (int o = 32; o > 0; o >>= 1) s += __shfl_xor(s, o);
      float inv = 1.0f / fmaxf(sqrtf(s), EPSN);
      union { ushort4 u4; unsigned short us[4]; } o;
      float f0 = v.x * inv, f1 = v.y * inv, f2 = v.z * inv, f3 = v.w * inv;
      __bf16 h0 = (__bf16)f0, h1 = (__bf16)f1, h2 = (__bf16)f2, h3 = (__bf16)f3;
      o.us[0] = *reinterpret_cast<unsigned short*>(&h0);
      o.us[1] = *reinterpret_cast<unsigned short*>(&h1);
      o.us[2] = *reinterpret_cast<unsigned short*>(&h2);
      o.us[3] = *reinterpret_cast<unsigned short*>(&h3);
      reinterpret_cast<ushort4*>(pn + (size_t)b * DD)[lane] = o.u4;
    }
    asm volatile("" ::: "memory");  // force real re-execution per rep
  }
}

// K2: one block per class; scan cls (64KB, L2-hot), LDS row list, gather ~8
// preds rows, mean, normalize -> cn bf16 + exists (+ Ecnt on rep 0 only).
__global__ __launch_bounds__(256) void k_cn(const float* __restrict__ preds,
                                            const int* __restrict__ cls,
                                            unsigned short* __restrict__ cn,
                                            int* __restrict__ exists,
                                            int* __restrict__ Ecnt) {
  int c = blockIdx.x;
  int t = threadIdx.x;
  __shared__ int s_cnt;
  __shared__ int s_rows[SLOTS];
  __shared__ float red[4];
  for (int rep = 0; rep < REP_CN; ++rep) {
    if (t == 0) s_cnt = 0;
    __syncthreads();
    for (int i = t; i < BB; i += 256) {
      if (cls[i] == c) {
        int slot = atomicAdd(&s_cnt, 1);
        if (slot < SLOTS) s_rows[slot] = i;
      }
    }
    __syncthreads();
    int n = s_cnt;
    int nn = n < SLOTS ? n : SLOTS;
    float sum = 0.f;
    for (int i = 0; i < nn; ++i)
      sum += preds[(size_t)s_rows[i] * DD + t];
    float mean = sum / (float)(n > 0 ? n : 1);
    float ss = mean * mean;
#pragma unroll
    for (int o = 32; o > 0; o >>= 1) ss += __shfl_xor(ss, o);
    int wave = t >> 6, lane = t & 63;
    if (lane == 0) red[wave] = ss;
    __syncthreads();
    float tot = red[0] + red[1] + red[2] + red[3];
    float inv = 1.0f / fmaxf(sqrtf(tot), EPSN);
    __bf16 h = (__bf16)(mean * inv);
    cn[(size_t)c * DD + t] = *reinterpret_cast<unsigned short*>(&h);
    if (rep == 0 && t == 0) {
      exists[c] = (n > 0) ? 1 : 0;
      if (n > 0) atomicAdd(Ecnt, 1);
    }
    __syncthreads();                // all reads of s_* done before next rep
    asm volatile("" ::: "memory");
  }
}

// K3: r4-exact GEMM structure, K-sweep linearized x8 (32 steps, s -> ks=s&3),
// acc accumulates 8*cos; epilogue scales by 1/8 (exact).
// Swizzle (rule #21, both-sides, conflict-free r2-r8): element (row,kb) at
// byte row*128 + (kb ^ ((row&7)<<4)); gload_lds dest linear, SOURCE
// inverse-permuted, ds_read same XOR.

__device__ __forceinline__ void stage32k(char* lds, const char* gsrc_row0,
                                         int tid, int ksbyte) {
#pragma unroll
  for (int i = 0; i < 4; ++i) {
    int L = i * 8192 + tid * 16;             // linear LDS byte (32KB / 512thr)
    int row = L >> 7;                        // 128B per row (64 k * 2B)
    int kb  = (L & 127) ^ ((row & 7) << 4);  // involution
    const char* g = gsrc_row0 + (size_t)row * (DD * 2) + ksbyte + kb;
    __builtin_amdgcn_global_load_lds(
        (const __attribute__((address_space(1))) unsigned int*)g,
        (__attribute__((address_space(3))) unsigned int*)(lds + L), 16, 0, 0);
  }
}

__device__ __forceinline__ bf16x8 ldfrag(const char* buf, int row, int kb) {
  return *reinterpret_cast<const bf16x8*>(buf + row * 128 + (kb ^ ((row & 7) << 4)));
}

__global__ __launch_bounds__(512, 2) void k_loss(
    const unsigned short* __restrict__ pn, const unsigned short* __restrict__ cn,
    const int* __restrict__ cls, const int* __restrict__ exists,
    const int* __restrict__ Ecnt, float* __restrict__ out) {
  constexpr int BM = 256, BN = 256;
  __shared__ __align__(16) char sA[2][BM * 64 * 2];   // 2 x 32KB
  __shared__ __align__(16) char sB[2][BN * 64 * 2];   // 2 x 32KB
  __shared__ float red[8];

  // 512 blocks = 64 mtiles x 8 ntiles; bijective XCD swizzle (512 % 8 == 0).
  int bid = blockIdx.x;
  int nb = (bid & 7) * 64 + (bid >> 3);
  int mtile = nb & 63;
  int ntile = nb >> 6;
  int rowbase = mtile * BM, colbase = ntile * BN;
  int tid = threadIdx.x, w = tid >> 6, lane = tid & 63;
  int wm = w >> 2, wn = w & 3;            // wave grid 2 x 4
  int r16 = lane & 15, khi = lane >> 4;   // khi in 0..3
  int arow0 = wm * 128 + r16;             // LDS-A row base for a-frags
  int brow0 = wn * 64 + r16;              // LDS-B row base for b-frags

  const char* pnB = (const char*)pn + (size_t)rowbase * (DD * 2);
  const char* cnB = (const char*)cn + (size_t)colbase * (DD * 2);

  f32x4 acc[8][4];
#pragma unroll
  for (int m = 0; m < 8; ++m)
#pragma unroll
    for (int n = 0; n < 4; ++n) acc[m][n] = {0.f, 0.f, 0.f, 0.f};

  stage32k(sA[0], pnB, tid, 0);
  stage32k(sB[0], cnB, tid, 0);
  __syncthreads();

  int cur = 0;
  for (int s = 0; s < 4 * REP_LOSS; ++s) {  // 8 reps x 4 K-steps, linearized
    if (s < 4 * REP_LOSS - 1) {
      int nxt = ((s + 1) & 3) * 128;        // K-byte offset of next step
      stage32k(sA[cur ^ 1], pnB, tid, nxt);
      stage32k(sB[cur ^ 1], cnB, tid, nxt);
    }
    const char* bufA = sA[cur];
    const char* bufB = sB[cur];
#pragma unroll
    for (int kk = 0; kk < 2; ++kk) {        // 2 x K=32 per BK=64
      int kb = kk * 64 + khi * 16;
      bf16x8 b[4];
#pragma unroll
      for (int n = 0; n < 4; ++n) b[n] = ldfrag(bufB, brow0 + n * 16, kb);
#pragma unroll
      for (int m = 0; m < 8; ++m) {
        bf16x8 a = ldfrag(bufA, arow0 + m * 16, kb);
#pragma unroll
        for (int n = 0; n < 4; ++n)
          acc[m][n] = __builtin_amdgcn_mfma_f32_16x16x32_bf16(a, b[n], acc[m][n], 0, 0, 0);
      }
    }
    __syncthreads();                        // staged loads landed + reads done
    cur ^= 1;
  }

  // Epilogue: v = acc/8, then pos (diagonal) + hinge neg -> scalar atomic.
  // D layout: col = lane&15, row = (lane>>4)*4 + reg  (m89-verified)
  constexpr float SCALE = 1.0f / (float)REP_LOSS;   // 0.125 exact
  int E = *Ecnt;
  float inv_B = 1.0f / (float)BB;
  float inv_neg = inv_B / (float)((E - 1) > 0 ? (E - 1) : 1);
  int grow0 = rowbase + wm * 128;

  int clsr[8][4];
#pragma unroll
  for (int m = 0; m < 8; ++m)
#pragma unroll
    for (int r = 0; r < 4; ++r) clsr[m][r] = cls[grow0 + m * 16 + khi * 4 + r];
  int exs[4];
#pragma unroll
  for (int n = 0; n < 4; ++n) exs[n] = exists[colbase + wn * 64 + n * 16 + r16];

  float local = 0.f;
#pragma unroll
  for (int m = 0; m < 8; ++m)
#pragma unroll
    for (int n = 0; n < 4; ++n) {
      int ccol = colbase + wn * 64 + n * 16 + r16;
#pragma unroll
      for (int r = 0; r < 4; ++r) {
        float v = acc[m][n][r] * SCALE;
        if (ccol == clsr[m][r])
          local += (1.0f - v) * inv_B;              // pos: 1 - cos(b, cls[b])
        else if (exs[n])
          local += fmaxf(v - 0.7f, 0.f) * inv_neg;  // relu(M_NEG - (1 - cos))
      }
    }

#pragma unroll
  for (int o = 32; o > 0; o >>= 1) local += __shfl_xor(local, o);
  if (lane == 0) red[w] = local;
  __syncthreads();
  if (tid == 0) {
    float t = 0.f;
#pragma unroll
    for (int i = 0; i < 8; ++i) t += red[i];
    atomicAdd(out, t);
  }
}

extern "C" void kernel_launch(void* const* d_in, const int* in_sizes, int n_in,
                              void* d_out, int out_size, void* d_ws, size_t ws_size,
                              hipStream_t stream) {
  const float* preds  = (const float*)d_in[0];
  const float* labels = (const float*)d_in[1];
  float* out = (float*)d_out;

  char* ws = (char*)d_ws;
  int*            cls    = (int*)(ws + 0);
  int*            exists = (int*)(ws + 65536);
  int*            Ecnt   = (int*)(ws + 73728);
  unsigned short* pn     = (unsigned short*)(ws + 73792);
  unsigned short* cn     = (unsigned short*)(ws + 8462400);

  k_scan_pn<<<6144, 256, 0, stream>>>(labels, preds, cls, pn, Ecnt, out);
  k_cn<<<CC, 256, 0, stream>>>(preds, cls, cn, exists, Ecnt);
  k_loss<<<512, 512, 0, stream>>>(pn, cn, cls, exists, Ecnt, out);
}

// Round 10
// 95.934 us; speedup vs baseline: 6.5848x; 6.5848x over previous
//
#include <hip/hip_runtime.h>
#include <hip/hip_bf16.h>

// Problem constants (match reference)
constexpr int BB = 16384;   // batch
constexpr int CC = 2048;    // classes
constexpr int DD = 256;     // dim
constexpr float THR   = 0.8f;
constexpr float EPSN  = 1e-8f;

typedef __bf16 bf16x8 __attribute__((ext_vector_type(8)));
typedef float  f32x4  __attribute__((ext_vector_type(4)));

// ---------------- workspace layout (bytes) ----------------
// [0)         cnt     : C*4   = 8,192      (zeroed each launch via memset)
// [8,192)     Ecnt    : 4 (pad to 8,256)   (zeroed via memset)
// [8,256)     cls     : B*4   = 65,536
// [73,792)    rowlist : C*64*4 = 524,288   (slot-guarded, no zero needed)
// [598,080)   exists  : C*4   = 8,192
// [606,272)   pn      : B*D*2 = 8,388,608  (bf16)
// [8,994,880) cn      : C*D*2 = 1,048,576  (bf16)
//
// ROUND-10 LEDGER (measured r5/r6/r9 instruments):
//   scan_pn ~26us = 97% of 159MB/6.3TB/s HBM roofline
//   cn(gather) ~4us   (r8's cls-scan variant measured 13.1us -> reverted)
//   loss ~12.2us = 1408 TF (56% dense peak, K=256 small-K GEMM)
//   fixed harness residual F ~53us (invariant across 3..6 nodes; r7's
//   cooperative fusion made it worse via XCD cache flush)
constexpr int ROWSLOTS = 64;  // Poisson(8) max over 2048 classes << 64

// K1 fat kernel: blocks [0,2048) stream labels -> cls/cnt/rowlist (+ out=0);
// blocks [2048,6144) normalize preds -> pn (bf16), 1 wave/row.
__global__ __launch_bounds__(256) void k_prep(const float* __restrict__ labels,
                                              const float* __restrict__ preds,
                                              int* __restrict__ cls,
                                              int* __restrict__ cnt,
                                              int* __restrict__ rowlist,
                                              unsigned short* __restrict__ pn,
                                              float* __restrict__ out) {
  if (blockIdx.x < 2048) {
    if (blockIdx.x == 0 && threadIdx.x == 0) *out = 0.f;
    constexpr size_t total = (size_t)BB * CC / 4;
    size_t q = (size_t)blockIdx.x * 256 + threadIdx.x;
    const float4* l4 = reinterpret_cast<const float4*>(labels);
    for (; q < total; q += 2048 * 256) {
      float4 v = l4[q];
      if (v.x >= THR || v.y >= THR || v.z >= THR || v.w >= THR) {
        int f = (int)(q * 4);
        int row = f >> 11;      // / CC
        int col = f & (CC - 1);
        int c = col + (v.x >= THR ? 0 : v.y >= THR ? 1 : v.z >= THR ? 2 : 3);
        cls[row] = c;
        int s = atomicAdd(&cnt[c], 1);
        if (s < ROWSLOTS) rowlist[c * ROWSLOTS + s] = row;
      }
    }
  } else {
    int b = (blockIdx.x - 2048) * 4 + (threadIdx.x >> 6);
    int lane = threadIdx.x & 63;
    float4 v = reinterpret_cast<const float4*>(preds + (size_t)b * DD)[lane];
    float s = v.x * v.x + v.y * v.y + v.z * v.z + v.w * v.w;
#pragma unroll
    for (int o = 32; o > 0; o >>= 1) s += __shfl_xor(s, o);
    float inv = 1.0f / fmaxf(sqrtf(s), EPSN);
    union { ushort4 u4; unsigned short us[4]; } o;
    float f0 = v.x * inv, f1 = v.y * inv, f2 = v.z * inv, f3 = v.w * inv;
    __bf16 h0 = (__bf16)f0, h1 = (__bf16)f1, h2 = (__bf16)f2, h3 = (__bf16)f3;
    o.us[0] = *reinterpret_cast<unsigned short*>(&h0);
    o.us[1] = *reinterpret_cast<unsigned short*>(&h1);
    o.us[2] = *reinterpret_cast<unsigned short*>(&h2);
    o.us[3] = *reinterpret_cast<unsigned short*>(&h3);
    reinterpret_cast<ushort4*>(pn + (size_t)b * DD)[lane] = o.u4;
  }
}

// K2: per-class gather (~8 rows via rowlist), mean, normalize -> cn bf16 +
// exists + Ecnt. Measured-fast variant (no per-block cls scan).
__global__ __launch_bounds__(256) void k_cn(
    const float* __restrict__ preds, const int* __restrict__ cnt,
    const int* __restrict__ rowlist, unsigned short* __restrict__ cn,
    int* __restrict__ exists, int* __restrict__ Ecnt) {
  int c = blockIdx.x;
  int t = threadIdx.x;
  int n = cnt[c];
  int nn = n < ROWSLOTS ? n : ROWSLOTS;
  float sum = 0.f;
  for (int i = 0; i < nn; ++i) {
    int row = rowlist[c * ROWSLOTS + i];
    sum += preds[(size_t)row * DD + t];
  }
  float mean = sum / (float)(n > 0 ? n : 1);
  float s = mean * mean;
#pragma unroll
  for (int o = 32; o > 0; o >>= 1) s += __shfl_xor(s, o);
  __shared__ float red[4];
  int wave = t >> 6, lane = t & 63;
  if (lane == 0) red[wave] = s;
  __syncthreads();
  float tot = red[0] + red[1] + red[2] + red[3];
  float inv = 1.0f / fmaxf(sqrtf(tot), EPSN);
  __bf16 h = (__bf16)(mean * inv);
  cn[c * DD + t] = *reinterpret_cast<unsigned short*>(&h);
  if (t == 0) {
    exists[c] = (n > 0) ? 1 : 0;
    if (n > 0) atomicAdd(Ecnt, 1);
  }
}

// K3: GEMM, 256x256 tile, BK=64, 8 waves, dbuf 128KB LDS, fused epilogue.
// Measured 12.2us (r6 amplification) = 1408 TF effective.
// Swizzle (rule #21, both-sides, conflict-free r2-r9): element (row,kb) at
// byte row*128 + (kb ^ ((row&7)<<4)); gload_lds dest linear, SOURCE
// inverse-permuted, ds_read same XOR.

__device__ __forceinline__ void stage32k(char* lds, const char* gsrc_row0,
                                         int tid, int ksbyte) {
#pragma unroll
  for (int i = 0; i < 4; ++i) {
    int L = i * 8192 + tid * 16;             // linear LDS byte (32KB / 512thr)
    int row = L >> 7;                        // 128B per row (64 k * 2B)
    int kb  = (L & 127) ^ ((row & 7) << 4);  // involution
    const char* g = gsrc_row0 + (size_t)row * (DD * 2) + ksbyte + kb;
    __builtin_amdgcn_global_load_lds(
        (const __attribute__((address_space(1))) unsigned int*)g,
        (__attribute__((address_space(3))) unsigned int*)(lds + L), 16, 0, 0);
  }
}

__device__ __forceinline__ bf16x8 ldfrag(const char* buf, int row, int kb) {
  return *reinterpret_cast<const bf16x8*>(buf + row * 128 + (kb ^ ((row & 7) << 4)));
}

__global__ __launch_bounds__(512, 2) void k_loss(
    const unsigned short* __restrict__ pn, const unsigned short* __restrict__ cn,
    const int* __restrict__ cls, const int* __restrict__ exists,
    const int* __restrict__ Ecnt, float* __restrict__ out) {
  constexpr int BM = 256, BN = 256;
  __shared__ __align__(16) char sA[2][BM * 64 * 2];   // 2 x 32KB
  __shared__ __align__(16) char sB[2][BN * 64 * 2];   // 2 x 32KB
  __shared__ float red[8];

  // 512 blocks = 64 mtiles x 8 ntiles; bijective XCD swizzle (512 % 8 == 0).
  int bid = blockIdx.x;
  int nb = (bid & 7) * 64 + (bid >> 3);
  int mtile = nb & 63;
  int ntile = nb >> 6;
  int rowbase = mtile * BM, colbase = ntile * BN;
  int tid = threadIdx.x, w = tid >> 6, lane = tid & 63;
  int wm = w >> 2, wn = w & 3;            // wave grid 2 x 4
  int r16 = lane & 15, khi = lane >> 4;   // khi in 0..3
  int arow0 = wm * 128 + r16;             // LDS-A row base for a-frags
  int brow0 = wn * 64 + r16;              // LDS-B row base for b-frags

  const char* pnB = (const char*)pn + (size_t)rowbase * (DD * 2);
  const char* cnB = (const char*)cn + (size_t)colbase * (DD * 2);

  f32x4 acc[8][4];
#pragma unroll
  for (int m = 0; m < 8; ++m)
#pragma unroll
    for (int n = 0; n < 4; ++n) acc[m][n] = {0.f, 0.f, 0.f, 0.f};

  stage32k(sA[0], pnB, tid, 0);
  stage32k(sB[0], cnB, tid, 0);
  __syncthreads();

  int cur = 0;
#pragma unroll
  for (int ks = 0; ks < 4; ++ks) {        // 256 / BK = 4 K-steps
    if (ks < 3) {                         // issue next stage BEFORE compute
      stage32k(sA[cur ^ 1], pnB, tid, (ks + 1) * 128);
      stage32k(sB[cur ^ 1], cnB, tid, (ks + 1) * 128);
    }
    const char* bufA = sA[cur];
    const char* bufB = sB[cur];
#pragma unroll
    for (int kk = 0; kk < 2; ++kk) {      // 2 x K=32 per BK=64
      int kb = kk * 64 + khi * 16;
      bf16x8 b[4];
#pragma unroll
      for (int n = 0; n < 4; ++n) b[n] = ldfrag(bufB, brow0 + n * 16, kb);
#pragma unroll
      for (int m = 0; m < 8; ++m) {
        bf16x8 a = ldfrag(bufA, arow0 + m * 16, kb);
#pragma unroll
        for (int n = 0; n < 4; ++n)
          acc[m][n] = __builtin_amdgcn_mfma_f32_16x16x32_bf16(a, b[n], acc[m][n], 0, 0, 0);
      }
    }
    __syncthreads();                      // staged loads landed + reads done
    cur ^= 1;
  }

  // Epilogue (verified r1-r9): pos (diagonal) + hinge neg -> scalar atomic.
  // D layout: col = lane&15, row = (lane>>4)*4 + reg  (m89-verified)
  int E = *Ecnt;
  float inv_B = 1.0f / (float)BB;
  float inv_neg = inv_B / (float)((E - 1) > 0 ? (E - 1) : 1);
  int grow0 = rowbase + wm * 128;

  int clsr[8][4];
#pragma unroll
  for (int m = 0; m < 8; ++m)
#pragma unroll
    for (int r = 0; r < 4; ++r) clsr[m][r] = cls[grow0 + m * 16 + khi * 4 + r];
  int exs[4];
#pragma unroll
  for (int n = 0; n < 4; ++n) exs[n] = exists[colbase + wn * 64 + n * 16 + r16];

  float local = 0.f;
#pragma unroll
  for (int m = 0; m < 8; ++m)
#pragma unroll
    for (int n = 0; n < 4; ++n) {
      int ccol = colbase + wn * 64 + n * 16 + r16;
#pragma unroll
      for (int r = 0; r < 4; ++r) {
        float v = acc[m][n][r];
        if (ccol == clsr[m][r])
          local += (1.0f - v) * inv_B;              // pos: 1 - cos(b, cls[b])
        else if (exs[n])
          local += fmaxf(v - 0.7f, 0.f) * inv_neg;  // relu(M_NEG - (1 - cos))
      }
    }

#pragma unroll
  for (int o = 32; o > 0; o >>= 1) local += __shfl_xor(local, o);
  if (lane == 0) red[w] = local;
  __syncthreads();
  if (tid == 0) {
    float t = 0.f;
#pragma unroll
    for (int i = 0; i < 8; ++i) t += red[i];
    atomicAdd(out, t);
  }
}

extern "C" void kernel_launch(void* const* d_in, const int* in_sizes, int n_in,
                              void* d_out, int out_size, void* d_ws, size_t ws_size,
                              hipStream_t stream) {
  const float* preds  = (const float*)d_in[0];
  const float* labels = (const float*)d_in[1];
  float* out = (float*)d_out;

  char* ws = (char*)d_ws;
  int*            cnt     = (int*)(ws + 0);
  int*            Ecnt    = (int*)(ws + 8192);
  int*            cls     = (int*)(ws + 8256);
  int*            rowlist = (int*)(ws + 73792);
  int*            exists  = (int*)(ws + 598080);
  unsigned short* pn      = (unsigned short*)(ws + 606272);
  unsigned short* cn      = (unsigned short*)(ws + 8994880);

  hipMemsetAsync(ws, 0, 8256, stream);                 // cnt + Ecnt
  k_prep<<<6144, 256, 0, stream>>>(labels, preds, cls, cnt, rowlist, pn, out);
  k_cn<<<CC, 256, 0, stream>>>(preds, cnt, rowlist, cn, exists, Ecnt);
  k_loss<<<512, 512, 0, stream>>>(pn, cn, cls, exists, Ecnt, out);
}